// Round 2
// baseline (494.758 us; speedup 1.0000x reference)
//
#include <hip/hip_runtime.h>
#include <hip/hip_bf16.h>
#include <cstdint>

#define B_SZ 2
#define S_LEN 4096
#define R_TOT 8192      // B*S
#define DM 2048
#define NH 16
#define DK 128
#define NFEAT 8
#define CHUNK 128
#define NCHUNK 32       // S_LEN / CHUNK
#define EPSF 1e-6f

typedef short bf16x8_t __attribute__((ext_vector_type(8)));
typedef float f32x4_t __attribute__((ext_vector_type(4)));

__device__ __forceinline__ ushort f2bf(float f) {
  uint32_t u = __float_as_uint(f);
  u += 0x7FFF + ((u >> 16) & 1);           // RNE
  return (ushort)(u >> 16);
}
__device__ __forceinline__ float bf2f(ushort u) {
  return __uint_as_float(((uint32_t)u) << 16);
}

// ---------------- cast fp32 -> bf16, float4 vectorized ----------------
__global__ __launch_bounds__(256) void cast_f32_bf16(const float* __restrict__ src,
                                                     ushort* __restrict__ dst, int n4) {
  int i = blockIdx.x * 256 + threadIdx.x;
  if (i >= n4) return;
  float4 f = reinterpret_cast<const float4*>(src)[i];
  ushort4 o;
  o.x = f2bf(f.x); o.y = f2bf(f.y); o.z = f2bf(f.z); o.w = f2bf(f.w);
  reinterpret_cast<ushort4*>(dst)[i] = o;
}

// ---------------- fold omega into projection weight ----------------
// O[(h*8+n)*2048 + j] = sum_d W[(h*128+d)*2048 + j] * omega[n*128+d]   (fp32, out bf16)
__global__ __launch_bounds__(256) void fold_kernel(const float* __restrict__ W,
                                                   const float* __restrict__ omega,
                                                   ushort* __restrict__ O) {
  __shared__ float som[NFEAT * DK];
  const int h = blockIdx.y;
  const int j = blockIdx.x * 256 + threadIdx.x;
  for (int i = threadIdx.x; i < NFEAT * DK; i += 256) som[i] = omega[i];
  __syncthreads();
  float acc[NFEAT] = {0.f, 0.f, 0.f, 0.f, 0.f, 0.f, 0.f, 0.f};
  for (int d = 0; d < DK; d++) {
    const float w = W[(size_t)(h * DK + d) * DM + j];
#pragma unroll
    for (int n = 0; n < NFEAT; n++) acc[n] += w * som[n * DK + d];
  }
#pragma unroll
  for (int n = 0; n < NFEAT; n++) O[(size_t)(h * NFEAT + n) * DM + j] = f2bf(acc[n]);
}

// ---------------- bf16 GEMM, C = A(MxK) * B(NxK)^T, m97 structure ----------------
// 128x128 tile, BK=32, 4 waves (2x2), each wave 64x64 via 4x4 MFMA 16x16x32 frags.
template<int BF16OUT>
__global__ __launch_bounds__(256) void gemm_bt(const ushort* __restrict__ A,
                                               const ushort* __restrict__ Bm,
                                               void* __restrict__ Cv,
                                               int M, int N, int K) {
  __shared__ ushort lds_a[128 * 32];
  __shared__ ushort lds_b[128 * 32];
  const int t = threadIdx.x;
  const int wave = t >> 6, lane = t & 63;
  const int m0 = blockIdx.y * 128, n0 = blockIdx.x * 128;
  const int wm = wave >> 1, wn = wave & 1;

  f32x4_t acc[4][4];
#pragma unroll
  for (int i = 0; i < 4; i++)
#pragma unroll
    for (int j = 0; j < 4; j++) acc[i][j] = (f32x4_t){0.f, 0.f, 0.f, 0.f};

  const int srow = lane >> 2;          // 0..15 within 16-row group
  const int skoff = (lane & 3) * 8;    // bf16 elems within K-step

  for (int k0 = 0; k0 < K; k0 += 32) {
#pragma unroll
    for (int i = 0; i < 2; i++) {
      const int rgrp = i * 4 + wave;         // 0..7 group of 16 rows
      const int row = rgrp * 16 + srow;
      const ushort* ga = A + (size_t)(m0 + row) * K + (k0 + skoff);
      const ushort* gb = Bm + (size_t)(n0 + row) * K + (k0 + skoff);
      __builtin_amdgcn_global_load_lds(
          (const __attribute__((address_space(1))) void*)ga,
          (__attribute__((address_space(3))) void*)(lds_a + rgrp * 512), 16, 0, 0);
      __builtin_amdgcn_global_load_lds(
          (const __attribute__((address_space(1))) void*)gb,
          (__attribute__((address_space(3))) void*)(lds_b + rgrp * 512), 16, 0, 0);
    }
    __syncthreads();
    bf16x8_t af[4], bfr[4];
#pragma unroll
    for (int i = 0; i < 4; i++) {
      af[i]  = *reinterpret_cast<const bf16x8_t*>(
          lds_a + (wm * 64 + i * 16 + (lane & 15)) * 32 + (lane >> 4) * 8);
      bfr[i] = *reinterpret_cast<const bf16x8_t*>(
          lds_b + (wn * 64 + i * 16 + (lane & 15)) * 32 + (lane >> 4) * 8);
    }
#pragma unroll
    for (int i = 0; i < 4; i++)
#pragma unroll
      for (int j = 0; j < 4; j++)
        acc[i][j] = __builtin_amdgcn_mfma_f32_16x16x32_bf16(af[i], bfr[j], acc[i][j], 0, 0, 0);
    __syncthreads();
  }

  // C/D layout: col = lane&15, row = (lane>>4)*4 + reg
#pragma unroll
  for (int i = 0; i < 4; i++) {
    const int rb = m0 + wm * 64 + i * 16 + (lane >> 4) * 4;
#pragma unroll
    for (int j = 0; j < 4; j++) {
      const int col = n0 + wn * 64 + j * 16 + (lane & 15);
#pragma unroll
      for (int r = 0; r < 4; r++) {
        float val = acc[i][j][r];
        if (BF16OUT)
          ((ushort*)Cv)[(size_t)(rb + r) * N + col] = f2bf(val);
        else
          ((float*)Cv)[(size_t)(rb + r) * N + col] = val;
      }
    }
  }
}

// ---------------- performer features from folded projections ----------------
// X[row][h*8+n] fp32 -> F[((h*2+b)*4096+s)*8+n] normalized
__global__ __launch_bounds__(256) void feat2_kernel(const float* __restrict__ X,
                                                    float* __restrict__ F) {
  const int g = blockIdx.x * 256 + threadIdx.x;     // 131072 total
  const int row = g >> 4, h = g & 15;
  const float4* xp = reinterpret_cast<const float4*>(X + (size_t)row * (NH * NFEAT) + h * NFEAT);
  const float4 a = xp[0], c = xp[1];
  float x[8] = {a.x, a.y, a.z, a.w, c.x, c.y, c.z, c.w};
  float f[8], s = 0.f;
#pragma unroll
  for (int n = 0; n < 8; n++) { f[n] = __expf(-0.5f * x[n] * x[n]); s += f[n]; }
  const float inv = 1.f / (s + EPSF);
  const int b = row >> 12, sidx = row & 4095;
  float* out = F + ((size_t)(h * 2 + b) * 4096 + sidx) * 8;
  float4 o0 = {f[0] * inv, f[1] * inv, f[2] * inv, f[3] * inv};
  float4 o1 = {f[4] * inv, f[5] * inv, f[6] * inv, f[7] * inv};
  reinterpret_cast<float4*>(out)[0] = o0;
  reinterpret_cast<float4*>(out)[1] = o1;
}

// ---------------- per-chunk partial sums: KV_c[8][128], K_c[8] ----------------
__global__ __launch_bounds__(128) void chunk_sum_kernel(const float* __restrict__ KF,
                                                        const ushort* __restrict__ VH,
                                                        float* __restrict__ CKV,
                                                        float* __restrict__ CK) {
  const int cid = blockIdx.x;
  const int c = cid & 31, bh = cid >> 5, b = bh >> 4, h = bh & 15;
  const int d = threadIdx.x;
  __shared__ float s_kf[CHUNK * 8];
  const size_t fbase = ((size_t)(h * 2 + b) * 4096 + (size_t)c * CHUNK) * 8;
  {
    float4 a0 = *reinterpret_cast<const float4*>(KF + fbase + d * 8);
    float4 a1 = *reinterpret_cast<const float4*>(KF + fbase + d * 8 + 4);
    *reinterpret_cast<float4*>(s_kf + d * 8) = a0;
    *reinterpret_cast<float4*>(s_kf + d * 8 + 4) = a1;
  }
  __syncthreads();
  float kv[8] = {0, 0, 0, 0, 0, 0, 0, 0};
  float ks = 0.f;
  const ushort* vp = VH + ((size_t)b * S_LEN + (size_t)c * CHUNK) * DM + h * DK + d;
  for (int s = 0; s < CHUNK; s++) {
    const float v = bf2f(vp[(size_t)s * DM]);
#pragma unroll
    for (int n = 0; n < 8; n++) kv[n] += s_kf[s * 8 + n] * v;
    ks += s_kf[s * 8 + (d & 7)];
  }
#pragma unroll
  for (int n = 0; n < 8; n++) CKV[((size_t)cid * 8 + n) * 128 + d] = kv[n];
  if (d < 8) CK[cid * 8 + d] = ks;
}

// ---------------- exclusive prefix over chunks, per (b,h), in place ----------------
__global__ __launch_bounds__(128) void chunk_scan_kernel(float* __restrict__ CKV,
                                                         float* __restrict__ CK) {
  const int bh = blockIdx.x;
  const int d = threadIdx.x;
  float run[8] = {0, 0, 0, 0, 0, 0, 0, 0};
  for (int c = 0; c < NCHUNK; c++) {
    const size_t base = (size_t)(bh * NCHUNK + c) * 8 * 128 + d;
#pragma unroll
    for (int n = 0; n < 8; n++) {
      const float tv = CKV[base + n * 128];
      CKV[base + n * 128] = run[n];
      run[n] += tv;
    }
  }
  if (d < 8) {
    float r = 0.f;
    for (int c = 0; c < NCHUNK; c++) {
      const int i = (bh * NCHUNK + c) * 8 + d;
      const float tv = CK[i]; CK[i] = r; r += tv;
    }
  }
}

// ---------------- in-chunk causal scan + query ----------------
__global__ __launch_bounds__(128) void attn_scan_kernel(const float* __restrict__ QF,
                                                        const float* __restrict__ KF,
                                                        const ushort* __restrict__ VH,
                                                        const float* __restrict__ CKV,
                                                        const float* __restrict__ CK,
                                                        ushort* __restrict__ AO) {
  const int cid = blockIdx.x;
  const int c = cid & 31, bh = cid >> 5, b = bh >> 4, h = bh & 15;
  const int d = threadIdx.x;
  __shared__ float s_qf[CHUNK * 8];
  __shared__ float s_kf[CHUNK * 8];
  const size_t fbase = ((size_t)(h * 2 + b) * 4096 + (size_t)c * CHUNK) * 8;
  {
    float4 a0 = *reinterpret_cast<const float4*>(QF + fbase + d * 8);
    float4 a1 = *reinterpret_cast<const float4*>(QF + fbase + d * 8 + 4);
    float4 b0 = *reinterpret_cast<const float4*>(KF + fbase + d * 8);
    float4 b1 = *reinterpret_cast<const float4*>(KF + fbase + d * 8 + 4);
    *reinterpret_cast<float4*>(s_qf + d * 8) = a0;
    *reinterpret_cast<float4*>(s_qf + d * 8 + 4) = a1;
    *reinterpret_cast<float4*>(s_kf + d * 8) = b0;
    *reinterpret_cast<float4*>(s_kf + d * 8 + 4) = b1;
  }
  float kv[8], krun[8];
#pragma unroll
  for (int n = 0; n < 8; n++) kv[n] = CKV[((size_t)cid * 8 + n) * 128 + d];
#pragma unroll
  for (int n = 0; n < 8; n++) krun[n] = CK[cid * 8 + n];
  __syncthreads();
  const size_t row0 = (size_t)b * S_LEN + (size_t)c * CHUNK;
  const ushort* vp = VH + row0 * DM + h * DK + d;
  ushort* op = AO + row0 * DM + h * DK + d;
  for (int s = 0; s < CHUNK; s++) {
    const float v = bf2f(vp[(size_t)s * DM]);
    float num = 0.f, den = 0.f;
#pragma unroll
    for (int n = 0; n < 8; n++) {
      const float kf = s_kf[s * 8 + n];
      kv[n] += kf * v;       // inclusive update first
      krun[n] += kf;
      const float qf = s_qf[s * 8 + n];
      num += qf * kv[n];
      den += qf * krun[n];
    }
    op[(size_t)s * DM] = f2bf(num / (den + EPSF));
  }
}

extern "C" void kernel_launch(void* const* d_in, const int* in_sizes, int n_in,
                              void* d_out, int out_size, void* d_ws, size_t ws_size,
                              hipStream_t stream) {
  const float* q     = (const float*)d_in[0];
  const float* k     = (const float*)d_in[1];
  const float* v     = (const float*)d_in[2];
  const float* w_q   = (const float*)d_in[3];
  const float* w_k   = (const float*)d_in[4];
  const float* w_v   = (const float*)d_in[5];
  const float* w_o   = (const float*)d_in[6];
  const float* omega = (const float*)d_in[7];

  // ---- workspace layout (total ~97 MB) ----
  char* ws = (char*)d_ws;
  const size_t DD2 = (size_t)DM * DM * 2;          //  8,388,608
  const size_t OD2 = (size_t)NH * NFEAT * DM * 2;  //    524,288
  const size_t RD2 = (size_t)R_TOT * DM * 2;       // 33,554,432
  const size_t X4  = (size_t)R_TOT * NH * NFEAT * 4; // 4,194,304

  ushort* wvb = (ushort*)(ws);
  ushort* wob = (ushort*)(ws + DD2);
  ushort* oqb = (ushort*)(ws + 2 * DD2);
  ushort* okb = (ushort*)(ws + 2 * DD2 + OD2);
  ushort* xb  = (ushort*)(ws + 2 * DD2 + 2 * OD2);               // bf16 staging: q -> k -> v -> attn-out
  ushort* vhb = (ushort*)(ws + 2 * DD2 + 2 * OD2 + RD2);
  float*  xh  = (float*) (ws + 2 * DD2 + 2 * OD2 + 2 * RD2);     // fp32 features pre-kernel (reused q -> k)
  float*  qf  = (float*) (ws + 2 * DD2 + 2 * OD2 + 2 * RD2 + X4);
  float*  kf  = (float*) (ws + 2 * DD2 + 2 * OD2 + 2 * RD2 + 2 * X4);
  float*  ckv = (float*) (ws + 2 * DD2 + 2 * OD2 + 2 * RD2 + 3 * X4);
  float*  ck  = (float*) (ws + 2 * DD2 + 2 * OD2 + 2 * RD2 + 4 * X4);
  ushort* ao  = xb;

  const int n4_in = R_TOT * DM / 4;   // 4,194,304
  const int n4_w  = DM * DM / 4;      // 1,048,576

  // weights
  cast_f32_bf16<<<dim3(n4_w / 256), 256, 0, stream>>>(w_v, wvb, n4_w);
  cast_f32_bf16<<<dim3(n4_w / 256), 256, 0, stream>>>(w_o, wob, n4_w);
  fold_kernel<<<dim3(DM / 256, NH), 256, 0, stream>>>(w_q, omega, oqb);
  fold_kernel<<<dim3(DM / 256, NH), 256, 0, stream>>>(w_k, omega, okb);

  dim3 gg_full(DM / 128, R_TOT / 128);   // (16, 64)
  dim3 gg_thin(1, R_TOT / 128);          // (1, 64)

  // q features
  cast_f32_bf16<<<dim3(n4_in / 256), 256, 0, stream>>>(q, xb, n4_in);
  gemm_bt<0><<<gg_thin, 256, 0, stream>>>(xb, oqb, (void*)xh, R_TOT, NH * NFEAT, DM);
  feat2_kernel<<<dim3(R_TOT * NH / 256), 256, 0, stream>>>(xh, qf);

  // k features
  cast_f32_bf16<<<dim3(n4_in / 256), 256, 0, stream>>>(k, xb, n4_in);
  gemm_bt<0><<<gg_thin, 256, 0, stream>>>(xb, okb, (void*)xh, R_TOT, NH * NFEAT, DM);
  feat2_kernel<<<dim3(R_TOT * NH / 256), 256, 0, stream>>>(xh, kf);

  // v projection
  cast_f32_bf16<<<dim3(n4_in / 256), 256, 0, stream>>>(v, xb, n4_in);
  gemm_bt<1><<<gg_full, 256, 0, stream>>>(xb, wvb, (void*)vhb, R_TOT, DM, DM);

  // causal linear attention scan
  chunk_sum_kernel<<<dim3(B_SZ * NH * NCHUNK), 128, 0, stream>>>(kf, vhb, ckv, ck);
  chunk_scan_kernel<<<dim3(B_SZ * NH), 128, 0, stream>>>(ckv, ck);
  attn_scan_kernel<<<dim3(B_SZ * NH * NCHUNK), 128, 0, stream>>>(qf, kf, vhb, ckv, ck, ao);

  // output projection
  gemm_bt<0><<<gg_full, 256, 0, stream>>>(ao, wob, d_out, R_TOT, DM, DM);
}

// Round 3
// 349.240 us; speedup vs baseline: 1.4167x; 1.4167x over previous
//
#include <hip/hip_runtime.h>
#include <hip/hip_bf16.h>
#include <cstdint>

#define B_SZ 2
#define S_LEN 4096
#define R_TOT 8192      // B*S
#define DM 2048
#define NH 16
#define DK 128
#define NFEAT 8
#define CHUNK 128
#define NCHUNK 32       // S_LEN / CHUNK
#define KSPL 512        // thin GEMM K-split size
#define EPSF 1e-6f

typedef short bf16x8_t __attribute__((ext_vector_type(8)));
typedef float f32x4_t __attribute__((ext_vector_type(4)));

__device__ __forceinline__ ushort f2bf(float f) {
  uint32_t u = __float_as_uint(f);
  u += 0x7FFF + ((u >> 16) & 1);           // RNE
  return (ushort)(u >> 16);
}
__device__ __forceinline__ float bf2f(ushort u) {
  return __uint_as_float(((uint32_t)u) << 16);
}

// ---------------- cast fp32 -> bf16, float4 vectorized ----------------
__global__ __launch_bounds__(256) void cast_f32_bf16(const float* __restrict__ src,
                                                     ushort* __restrict__ dst, int n4) {
  int i = blockIdx.x * 256 + threadIdx.x;
  if (i >= n4) return;
  float4 f = reinterpret_cast<const float4*>(src)[i];
  ushort4 o;
  o.x = f2bf(f.x); o.y = f2bf(f.y); o.z = f2bf(f.z); o.w = f2bf(f.w);
  reinterpret_cast<ushort4*>(dst)[i] = o;
}

// ---------------- fold omega into projection weight ----------------
// O[(h*8+n)*2048 + j] = sum_d W[(h*128+d)*2048 + j] * omega[n*128+d]
__global__ __launch_bounds__(256) void fold_kernel(const float* __restrict__ W,
                                                   const float* __restrict__ omega,
                                                   ushort* __restrict__ O) {
  __shared__ float som[NFEAT * DK];
  const int h = blockIdx.y;
  const int j = blockIdx.x * 256 + threadIdx.x;
  for (int i = threadIdx.x; i < NFEAT * DK; i += 256) som[i] = omega[i];
  __syncthreads();
  float acc[NFEAT] = {0.f, 0.f, 0.f, 0.f, 0.f, 0.f, 0.f, 0.f};
  for (int d = 0; d < DK; d++) {
    const float w = W[(size_t)(h * DK + d) * DM + j];
#pragma unroll
    for (int n = 0; n < NFEAT; n++) acc[n] += w * som[n * DK + d];
  }
#pragma unroll
  for (int n = 0; n < NFEAT; n++) O[(size_t)(h * NFEAT + n) * DM + j] = f2bf(acc[n]);
}

// ---------------- 256x256 deep-pipelined bf16 GEMM: C = A * B^T ----------------
// 8 waves (2Mx4N), BK=64 staged as two [256][32] K-half regions per tile,
// 2-buffer ring, counted vmcnt(4), XOR-swizzled LDS, setprio MFMA clusters.
template<int BF16OUT>
__global__ __launch_bounds__(512, 1) void gemm256(const ushort* __restrict__ A,
                                                  const ushort* __restrict__ Bm,
                                                  void* __restrict__ Cv,
                                                  int M, int N, int K) {
  __shared__ ushort lds[8 * 8192];     // [buf][A/B][kh] x (256*32), 128 KB
  const int tid = threadIdx.x;
  const int wave = tid >> 6, lane = tid & 63;
  const int wm = wave >> 2, wn = wave & 3;
  const int NKT = K >> 6;

  // bijective XCD swizzle (gridDim.x % 8 == 0)
  const int nb = N >> 8;
  const int cpx = gridDim.x >> 3;
  const int swz = (blockIdx.x & 7) * cpx + (blockIdx.x >> 3);
  const int bx = swz % nb, by = swz / nb;
  const int m0 = by * 256, n0 = bx * 256;

  auto stage = [&](int bufi, int ab, int kh, int kt, const ushort* G, int r0) {
    ushort* Lr = lds + (((bufi << 1) | ab) << 1 | kh) * 8192;
#pragma unroll
    for (int j = 0; j < 2; j++) {
      const int c = j * 512 + wave * 64 + lane;
      const int row = c >> 2, slot = c & 3;
      const int ss = slot ^ ((row >> 1) & 3);
      const ushort* g = G + (size_t)(r0 + row) * K + kt * 64 + kh * 32 + ss * 8;
      __builtin_amdgcn_global_load_lds(
          (const __attribute__((address_space(1))) void*)g,
          (__attribute__((address_space(3))) void*)(Lr + (j * 512 + wave * 64) * 8), 16, 0, 0);
    }
  };
  auto rdA = [&](int bufi, int kh, int m) -> bf16x8_t {
    const int row = wm * 128 + m * 16 + (lane & 15);
    const int slot = (lane >> 4) ^ ((row >> 1) & 3);
    return *reinterpret_cast<const bf16x8_t*>(lds + ((bufi << 2) | kh) * 8192 + row * 32 + slot * 8);
  };
  auto rdB = [&](int bufi, int kh, int nf) -> bf16x8_t {
    const int row = wn * 64 + nf * 16 + (lane & 15);
    const int slot = (lane >> 4) ^ ((row >> 1) & 3);
    return *reinterpret_cast<const bf16x8_t*>(lds + (((bufi << 1) | 1) << 1 | kh) * 8192 + row * 32 + slot * 8);
  };

  f32x4_t acc[8][4];
#pragma unroll
  for (int m = 0; m < 8; m++)
#pragma unroll
    for (int nf = 0; nf < 4; nf++) acc[m][nf] = (f32x4_t){0.f, 0.f, 0.f, 0.f};

  // prologue: tile0 (both K-halves) + tile1 kh0
  stage(0, 0, 0, 0, A, m0);  stage(0, 1, 0, 0, Bm, n0);
  stage(0, 0, 1, 0, A, m0);  stage(0, 1, 1, 0, Bm, n0);
  stage(1, 0, 0, 1, A, m0);  stage(1, 1, 0, 1, Bm, n0);
  asm volatile("s_waitcnt vmcnt(4)" ::: "memory");
  __builtin_amdgcn_s_barrier();
  __builtin_amdgcn_sched_barrier(0);

  bf16x8_t afr[8], b0, b1;
  for (int t = 0; t < NKT; t++) {
    const int buf = t & 1;
    // ---- phase 1: kh0, nf 0-1 ----
#pragma unroll
    for (int m = 0; m < 8; m++) afr[m] = rdA(buf, 0, m);
    b0 = rdB(buf, 0, 0); b1 = rdB(buf, 0, 1);
    if (t + 1 < NKT) { stage(buf ^ 1, 0, 1, t + 1, A, m0); stage(buf ^ 1, 1, 1, t + 1, Bm, n0); }
    __builtin_amdgcn_s_barrier();
    __builtin_amdgcn_s_setprio(1);
#pragma unroll
    for (int m = 0; m < 8; m++) {
      acc[m][0] = __builtin_amdgcn_mfma_f32_16x16x32_bf16(afr[m], b0, acc[m][0], 0, 0, 0);
      acc[m][1] = __builtin_amdgcn_mfma_f32_16x16x32_bf16(afr[m], b1, acc[m][1], 0, 0, 0);
    }
    __builtin_amdgcn_s_setprio(0);
    __builtin_amdgcn_s_barrier();
    __builtin_amdgcn_sched_barrier(0);
    // ---- phase 2: kh0, nf 2-3 ----
    b0 = rdB(buf, 0, 2); b1 = rdB(buf, 0, 3);
    __builtin_amdgcn_s_barrier();
    __builtin_amdgcn_s_setprio(1);
#pragma unroll
    for (int m = 0; m < 8; m++) {
      acc[m][2] = __builtin_amdgcn_mfma_f32_16x16x32_bf16(afr[m], b0, acc[m][2], 0, 0, 0);
      acc[m][3] = __builtin_amdgcn_mfma_f32_16x16x32_bf16(afr[m], b1, acc[m][3], 0, 0, 0);
    }
    __builtin_amdgcn_s_setprio(0);
    __builtin_amdgcn_s_barrier();
    __builtin_amdgcn_sched_barrier(0);
    // ---- phase 3: kh1, nf 0-1 (kh0 regions of this buf now dead -> restage) ----
#pragma unroll
    for (int m = 0; m < 8; m++) afr[m] = rdA(buf, 1, m);
    b0 = rdB(buf, 1, 0); b1 = rdB(buf, 1, 1);
    if (t + 2 < NKT) { stage(buf, 0, 0, t + 2, A, m0); stage(buf, 1, 0, t + 2, Bm, n0); }
    __builtin_amdgcn_s_barrier();
    __builtin_amdgcn_s_setprio(1);
#pragma unroll
    for (int m = 0; m < 8; m++) {
      acc[m][0] = __builtin_amdgcn_mfma_f32_16x16x32_bf16(afr[m], b0, acc[m][0], 0, 0, 0);
      acc[m][1] = __builtin_amdgcn_mfma_f32_16x16x32_bf16(afr[m], b1, acc[m][1], 0, 0, 0);
    }
    __builtin_amdgcn_s_setprio(0);
    __builtin_amdgcn_s_barrier();
    __builtin_amdgcn_sched_barrier(0);
    // ---- phase 4: kh1, nf 2-3 ----
    b0 = rdB(buf, 1, 2); b1 = rdB(buf, 1, 3);
    __builtin_amdgcn_s_barrier();
    __builtin_amdgcn_s_setprio(1);
#pragma unroll
    for (int m = 0; m < 8; m++) {
      acc[m][2] = __builtin_amdgcn_mfma_f32_16x16x32_bf16(afr[m], b0, acc[m][2], 0, 0, 0);
      acc[m][3] = __builtin_amdgcn_mfma_f32_16x16x32_bf16(afr[m], b1, acc[m][3], 0, 0, 0);
    }
    __builtin_amdgcn_s_setprio(0);
    if (t + 2 < NKT) { asm volatile("s_waitcnt vmcnt(4)" ::: "memory"); }
    else             { asm volatile("s_waitcnt vmcnt(0)" ::: "memory"); }
    __builtin_amdgcn_s_barrier();
    __builtin_amdgcn_sched_barrier(0);
  }

  // epilogue: C/D layout col = lane&15, row = (lane>>4)*4 + reg
#pragma unroll
  for (int m = 0; m < 8; m++) {
    const int rb = m0 + wm * 128 + m * 16 + (lane >> 4) * 4;
#pragma unroll
    for (int nf = 0; nf < 4; nf++) {
      const int col = n0 + wn * 64 + nf * 16 + (lane & 15);
#pragma unroll
      for (int r = 0; r < 4; r++) {
        const float val = acc[m][nf][r];
        if (BF16OUT)
          ((ushort*)Cv)[(size_t)(rb + r) * N + col] = f2bf(val);
        else
          ((float*)Cv)[(size_t)(rb + r) * N + col] = val;
      }
    }
  }
}

// ---------------- thin GEMM (N=128), split-K, m97 structure ----------------
// grid (4 splits, M/128); partial s -> P + s*M*128, fp32
__global__ __launch_bounds__(256) void gemm_thin(const ushort* __restrict__ A,
                                                 const ushort* __restrict__ Bm,
                                                 float* __restrict__ P,
                                                 int M, int K) {
  __shared__ ushort lds_a[128 * 32];
  __shared__ ushort lds_b[128 * 32];
  const int t = threadIdx.x;
  const int wave = t >> 6, lane = t & 63;
  const int spl = blockIdx.x;
  const int m0 = blockIdx.y * 128;
  const int kb = spl * KSPL;
  const int wm = wave >> 1, wn = wave & 1;

  f32x4_t acc[4][4];
#pragma unroll
  for (int i = 0; i < 4; i++)
#pragma unroll
    for (int j = 0; j < 4; j++) acc[i][j] = (f32x4_t){0.f, 0.f, 0.f, 0.f};

  const int srow = lane >> 2;
  const int skoff = (lane & 3) * 8;

  for (int k0 = kb; k0 < kb + KSPL; k0 += 32) {
#pragma unroll
    for (int i = 0; i < 2; i++) {
      const int rgrp = i * 4 + wave;
      const int row = rgrp * 16 + srow;
      const ushort* ga = A + (size_t)(m0 + row) * K + (k0 + skoff);
      const ushort* gb = Bm + (size_t)row * K + (k0 + skoff);
      __builtin_amdgcn_global_load_lds(
          (const __attribute__((address_space(1))) void*)ga,
          (__attribute__((address_space(3))) void*)(lds_a + rgrp * 512), 16, 0, 0);
      __builtin_amdgcn_global_load_lds(
          (const __attribute__((address_space(1))) void*)gb,
          (__attribute__((address_space(3))) void*)(lds_b + rgrp * 512), 16, 0, 0);
    }
    __syncthreads();
    bf16x8_t af[4], bfr[4];
#pragma unroll
    for (int i = 0; i < 4; i++) {
      af[i]  = *reinterpret_cast<const bf16x8_t*>(
          lds_a + (wm * 64 + i * 16 + (lane & 15)) * 32 + (lane >> 4) * 8);
      bfr[i] = *reinterpret_cast<const bf16x8_t*>(
          lds_b + (wn * 64 + i * 16 + (lane & 15)) * 32 + (lane >> 4) * 8);
    }
#pragma unroll
    for (int i = 0; i < 4; i++)
#pragma unroll
      for (int j = 0; j < 4; j++)
        acc[i][j] = __builtin_amdgcn_mfma_f32_16x16x32_bf16(af[i], bfr[j], acc[i][j], 0, 0, 0);
    __syncthreads();
  }

  float* Pp = P + (size_t)spl * ((size_t)R_TOT * 128);
#pragma unroll
  for (int i = 0; i < 4; i++) {
    const int rb = m0 + wm * 64 + i * 16 + (lane >> 4) * 4;
#pragma unroll
    for (int j = 0; j < 4; j++) {
      const int col = wn * 64 + j * 16 + (lane & 15);
#pragma unroll
      for (int r = 0; r < 4; r++)
        Pp[(size_t)(rb + r) * 128 + col] = acc[i][j][r];
    }
  }
}

// ---------------- performer features from 4 split-K partials ----------------
__global__ __launch_bounds__(256) void feat2_kernel(const float* __restrict__ P,
                                                    float* __restrict__ F) {
  const int g = blockIdx.x * 256 + threadIdx.x;     // 131072 total
  const int row = g >> 4, h = g & 15;
  float4 a = {0.f, 0.f, 0.f, 0.f}, c = {0.f, 0.f, 0.f, 0.f};
#pragma unroll
  for (int s = 0; s < 4; s++) {
    const float4* xp = reinterpret_cast<const float4*>(
        P + (size_t)s * ((size_t)R_TOT * 128) + (size_t)row * 128 + h * NFEAT);
    const float4 u = xp[0], w = xp[1];
    a.x += u.x; a.y += u.y; a.z += u.z; a.w += u.w;
    c.x += w.x; c.y += w.y; c.z += w.z; c.w += w.w;
  }
  float x[8] = {a.x, a.y, a.z, a.w, c.x, c.y, c.z, c.w};
  float f[8], s = 0.f;
#pragma unroll
  for (int n = 0; n < 8; n++) { f[n] = __expf(-0.5f * x[n] * x[n]); s += f[n]; }
  const float inv = 1.f / (s + EPSF);
  const int b = row >> 12, sidx = row & 4095;
  float* out = F + ((size_t)(h * 2 + b) * 4096 + sidx) * 8;
  float4 o0 = {f[0] * inv, f[1] * inv, f[2] * inv, f[3] * inv};
  float4 o1 = {f[4] * inv, f[5] * inv, f[6] * inv, f[7] * inv};
  reinterpret_cast<float4*>(out)[0] = o0;
  reinterpret_cast<float4*>(out)[1] = o1;
}

// ---------------- per-chunk partial sums: KV_c[8][128], K_c[8] ----------------
__global__ __launch_bounds__(128) void chunk_sum_kernel(const float* __restrict__ KF,
                                                        const ushort* __restrict__ VH,
                                                        float* __restrict__ CKV,
                                                        float* __restrict__ CK) {
  const int cid = blockIdx.x;
  const int c = cid & 31, bh = cid >> 5, b = bh >> 4, h = bh & 15;
  const int d = threadIdx.x;
  __shared__ float s_kf[CHUNK * 8];
  const size_t fbase = ((size_t)(h * 2 + b) * 4096 + (size_t)c * CHUNK) * 8;
  {
    float4 a0 = *reinterpret_cast<const float4*>(KF + fbase + d * 8);
    float4 a1 = *reinterpret_cast<const float4*>(KF + fbase + d * 8 + 4);
    *reinterpret_cast<float4*>(s_kf + d * 8) = a0;
    *reinterpret_cast<float4*>(s_kf + d * 8 + 4) = a1;
  }
  __syncthreads();
  float kv[8] = {0, 0, 0, 0, 0, 0, 0, 0};
  float ks = 0.f;
  const ushort* vp = VH + ((size_t)b * S_LEN + (size_t)c * CHUNK) * DM + h * DK + d;
  for (int s = 0; s < CHUNK; s++) {
    const float v = bf2f(vp[(size_t)s * DM]);
#pragma unroll
    for (int n = 0; n < 8; n++) kv[n] += s_kf[s * 8 + n] * v;
    ks += s_kf[s * 8 + (d & 7)];
  }
#pragma unroll
  for (int n = 0; n < 8; n++) CKV[((size_t)cid * 8 + n) * 128 + d] = kv[n];
  if (d < 8) CK[cid * 8 + d] = ks;
}

// ---------------- exclusive prefix over chunks, parallel ----------------
// block = (bh, n): 256 blocks x 128 threads; register-resident 32-chunk scan
__global__ __launch_bounds__(128) void chunk_scan2(float* __restrict__ CKV,
                                                   float* __restrict__ CK) {
  const int bh = blockIdx.x >> 3, n = blockIdx.x & 7;
  const int d = threadIdx.x;
  float v[NCHUNK];
#pragma unroll
  for (int c = 0; c < NCHUNK; c++)
    v[c] = CKV[((size_t)(bh * NCHUNK + c) * 8 + n) * 128 + d];
  float run = 0.f;
#pragma unroll
  for (int c = 0; c < NCHUNK; c++) {
    const float tv = v[c];
    CKV[((size_t)(bh * NCHUNK + c) * 8 + n) * 128 + d] = run;
    run += tv;
  }
  if (d < 32) {
    const int i = (bh * NCHUNK + d) * 8 + n;
    const float orig = CK[i];
    float inc = orig;
#pragma unroll
    for (int off = 1; off < 32; off <<= 1) {
      const float o = __shfl_up(inc, off, 32);
      if (d >= off) inc += o;
    }
    CK[i] = inc - orig;   // exclusive
  }
}

// ---------------- in-chunk causal scan + query ----------------
__global__ __launch_bounds__(128) void attn_scan_kernel(const float* __restrict__ QF,
                                                        const float* __restrict__ KF,
                                                        const ushort* __restrict__ VH,
                                                        const float* __restrict__ CKV,
                                                        const float* __restrict__ CK,
                                                        ushort* __restrict__ AO) {
  const int cid = blockIdx.x;
  const int c = cid & 31, bh = cid >> 5, b = bh >> 4, h = bh & 15;
  const int d = threadIdx.x;
  __shared__ float s_qf[CHUNK * 8];
  __shared__ float s_kf[CHUNK * 8];
  const size_t fbase = ((size_t)(h * 2 + b) * 4096 + (size_t)c * CHUNK) * 8;
  {
    float4 a0 = *reinterpret_cast<const float4*>(QF + fbase + d * 8);
    float4 a1 = *reinterpret_cast<const float4*>(QF + fbase + d * 8 + 4);
    float4 b0 = *reinterpret_cast<const float4*>(KF + fbase + d * 8);
    float4 b1 = *reinterpret_cast<const float4*>(KF + fbase + d * 8 + 4);
    *reinterpret_cast<float4*>(s_qf + d * 8) = a0;
    *reinterpret_cast<float4*>(s_qf + d * 8 + 4) = a1;
    *reinterpret_cast<float4*>(s_kf + d * 8) = b0;
    *reinterpret_cast<float4*>(s_kf + d * 8 + 4) = b1;
  }
  float kv[8], krun[8];
#pragma unroll
  for (int n = 0; n < 8; n++) kv[n] = CKV[((size_t)cid * 8 + n) * 128 + d];
#pragma unroll
  for (int n = 0; n < 8; n++) krun[n] = CK[cid * 8 + n];
  __syncthreads();
  const size_t row0 = (size_t)b * S_LEN + (size_t)c * CHUNK;
  const ushort* vp = VH + row0 * DM + h * DK + d;
  ushort* op = AO + row0 * DM + h * DK + d;
  for (int s = 0; s < CHUNK; s++) {
    const float v = bf2f(vp[(size_t)s * DM]);
    float num = 0.f, den = 0.f;
#pragma unroll
    for (int n = 0; n < 8; n++) {
      const float kf = s_kf[s * 8 + n];
      kv[n] += kf * v;       // inclusive update first
      krun[n] += kf;
      const float qf = s_qf[s * 8 + n];
      num += qf * kv[n];
      den += qf * krun[n];
    }
    op[(size_t)s * DM] = f2bf(num / (den + EPSF));
  }
}

extern "C" void kernel_launch(void* const* d_in, const int* in_sizes, int n_in,
                              void* d_out, int out_size, void* d_ws, size_t ws_size,
                              hipStream_t stream) {
  const float* q     = (const float*)d_in[0];
  const float* k     = (const float*)d_in[1];
  const float* v     = (const float*)d_in[2];
  const float* w_q   = (const float*)d_in[3];
  const float* w_k   = (const float*)d_in[4];
  const float* w_v   = (const float*)d_in[5];
  const float* w_o   = (const float*)d_in[6];
  const float* omega = (const float*)d_in[7];

  // ---- workspace layout (~93 MB) ----
  char* ws = (char*)d_ws;
  const size_t DD2 = (size_t)DM * DM * 2;            //  8 MB
  const size_t OD2 = (size_t)NH * NFEAT * DM * 2;    //  0.5 MB
  const size_t RD2 = (size_t)R_TOT * DM * 2;         // 32 MB
  const size_t X4  = (size_t)R_TOT * NH * NFEAT * 4; //  4 MB

  ushort* wvb = (ushort*)(ws);
  ushort* wob = (ushort*)(ws + DD2);
  ushort* oqb = (ushort*)(ws + 2 * DD2);
  ushort* okb = (ushort*)(ws + 2 * DD2 + OD2);
  ushort* xb  = (ushort*)(ws + 2 * DD2 + 2 * OD2);             // bf16 staging: q -> k -> v -> attn-out
  ushort* vhb = (ushort*)(ws + 2 * DD2 + 2 * OD2 + RD2);
  float*  xp4 = (float*) (ws + 2 * DD2 + 2 * OD2 + RD2);       // 4x fp32 partials (16MB) inside vhb region (dead then)
  float*  qf  = (float*) (ws + 2 * DD2 + 2 * OD2 + 2 * RD2);
  float*  kf  = (float*) (ws + 2 * DD2 + 2 * OD2 + 2 * RD2 + X4);
  float*  ckv = (float*) (ws + 2 * DD2 + 2 * OD2 + 2 * RD2 + 2 * X4);
  float*  ck  = (float*) (ws + 2 * DD2 + 2 * OD2 + 2 * RD2 + 3 * X4);
  ushort* ao  = xb;

  const int n4_in = R_TOT * DM / 4;
  const int n4_w  = DM * DM / 4;

  // weights
  cast_f32_bf16<<<dim3(n4_w / 256), 256, 0, stream>>>(w_v, wvb, n4_w);
  cast_f32_bf16<<<dim3(n4_w / 256), 256, 0, stream>>>(w_o, wob, n4_w);
  fold_kernel<<<dim3(DM / 256, NH), 256, 0, stream>>>(w_q, omega, oqb);
  fold_kernel<<<dim3(DM / 256, NH), 256, 0, stream>>>(w_k, omega, okb);

  dim3 gg_thin(DM / KSPL, R_TOT / 128);   // (4, 64) split-K

  // q features
  cast_f32_bf16<<<dim3(n4_in / 256), 256, 0, stream>>>(q, xb, n4_in);
  gemm_thin<<<gg_thin, 256, 0, stream>>>(xb, oqb, xp4, R_TOT, DM);
  feat2_kernel<<<dim3(R_TOT * NH / 256), 256, 0, stream>>>(xp4, qf);

  // k features
  cast_f32_bf16<<<dim3(n4_in / 256), 256, 0, stream>>>(k, xb, n4_in);
  gemm_thin<<<gg_thin, 256, 0, stream>>>(xb, okb, xp4, R_TOT, DM);
  feat2_kernel<<<dim3(R_TOT * NH / 256), 256, 0, stream>>>(xp4, kf);

  // v projection (overwrites xp4 region -- xp4 is dead now)
  cast_f32_bf16<<<dim3(n4_in / 256), 256, 0, stream>>>(v, xb, n4_in);
  gemm256<1><<<dim3((R_TOT / 256) * (DM / 256)), 512, 0, stream>>>(xb, wvb, (void*)vhb, R_TOT, DM, DM);

  // causal linear attention scan
  chunk_sum_kernel<<<dim3(B_SZ * NH * NCHUNK), 128, 0, stream>>>(kf, vhb, ckv, ck);
  chunk_scan2<<<dim3(B_SZ * NH * 8), 128, 0, stream>>>(ckv, ck);
  attn_scan_kernel<<<dim3(B_SZ * NH * NCHUNK), 128, 0, stream>>>(qf, kf, vhb, ckv, ck, ao);

  // output projection
  gemm256<0><<<dim3((R_TOT / 256) * (DM / 256)), 512, 0, stream>>>(ao, wob, d_out, R_TOT, DM, DM);
}